// Round 13
// baseline (254.411 us; speedup 1.0000x reference)
//
#include <hip/hip_runtime.h>

#define N_NODES 50000
#define DIM     128
#define N_EDGES 800000
#define N_LABEL 200000

// bucket partition: bucket = dst >> 7 (128 nodes/bucket), fixed capacity slots
#define NBUCK 391            // ceil(50000/128)
#define CAP   4096           // slots per bucket (mean fill ~2046, 40-sigma margin)
#define NPBLK 250            // partition blocks
#define CHUNK 3200           // edges per partition block

typedef __attribute__((ext_vector_type(8)))  short short8;    // 8 bf16 (4 VGPRs)
typedef __attribute__((ext_vector_type(16))) float floatx16;  // 32x32 MFMA acc

// split fp32 into bf16 hi + bf16 lo (x ~= hi + lo, rel err ~2^-17), RNE both
__device__ inline void f32_to_bf16x2(float x, unsigned short& hi, unsigned short& lo) {
    unsigned u  = __float_as_uint(x);
    unsigned rh = (u + 0x7FFFu + ((u >> 16) & 1u)) >> 16;
    hi = (unsigned short)rh;
    float hif = __uint_as_float(rh << 16);
    float r = x - hif;
    unsigned ul = __float_as_uint(r);
    unsigned rl = (ul + 0x7FFFu + ((ul >> 16) & 1u)) >> 16;
    lo = (unsigned short)rl;
}

__device__ inline unsigned short f32_to_bf16(float x) {
    unsigned u = __float_as_uint(x);
    return (unsigned short)((u + 0x7FFFu + ((u >> 16) & 1u)) >> 16);
}

__device__ inline unsigned pack_bf16x2(float a, float b) {
    return (unsigned)f32_to_bf16(a) | ((unsigned)f32_to_bf16(b) << 16);
}

__device__ inline float bf_lo(unsigned u) { return __uint_as_float(u << 16); }
__device__ inline float bf_hi(unsigned u) { return __uint_as_float(u & 0xFFFF0000u); }

// fused: [0,6250) build hb0 (bf16); [6250,6282) swizzle W; [6282,6532) partition scatter.
// bcount pre-zeroed by hipMemsetAsync. part record: src | (dst&127)<<16 (src<2^16).
__global__ __launch_bounds__(256)
void build_part(const int* __restrict__ n_id,
                const float* __restrict__ emb,
                const float* __restrict__ xs,
                unsigned* __restrict__ hb0,
                const float* __restrict__ W1l, const float* __restrict__ W1r,
                const float* __restrict__ W2l, const float* __restrict__ W2r,
                unsigned short* __restrict__ WfH, unsigned short* __restrict__ WfL,
                const int* __restrict__ src, const int* __restrict__ dst,
                int* __restrict__ bcount, unsigned* __restrict__ part) {
    __shared__ int hist[NBUCK];
    if (blockIdx.x < 6250) {
        int t = blockIdx.x * 256 + threadIdx.x;     // < N_NODES*32 exactly
        int i = t >> 5, c = t & 31;
        float4 v;
        if (c < 16) {
            int nid = n_id[i];
            v = ((const float4*)emb)[nid * 16 + c];
        } else {
            v = ((const float4*)xs)[i * 16 + (c - 16)];
        }
        uint2 p;
        p.x = pack_bf16x2(v.x, v.y);
        p.y = pack_bf16x2(v.z, v.w);
        ((uint2*)hb0)[i * 32 + c] = p;
    } else if (blockIdx.x < 6282) {
        int t = (blockIdx.x - 6250) * 256 + threadIdx.x;   // 8192 chunks
        if (t >= 8192) return;
        int L  = t & 63;
        int nt = (t >> 6) & 3;
        int ks = (t >> 8) & 7;
        int p  = (t >> 11) & 1;
        int ly = t >> 12;
        const float* Ws[4] = {W1l, W1r, W2l, W2r};
        const float* W = Ws[ly * 2 + p];
        int n = nt * 32 + (L & 31);
        int kbase = ks * 16 + (L >> 5) * 8;
        short8 hv, lv;
#pragma unroll
        for (int j = 0; j < 8; ++j) {
            unsigned short hh, ll;
            f32_to_bf16x2(W[(kbase + j) * DIM + n], hh, ll);
            hv[j] = (short)hh;
            lv[j] = (short)ll;
        }
        *(short8*)(WfH + (size_t)t * 8) = hv;
        *(short8*)(WfL + (size_t)t * 8) = lv;
    } else {
        // partition scatter: hist + range-reserve + grouped scatter
        int t = threadIdx.x;
        int blk = blockIdx.x - 6282;               // 0..NPBLK-1
        for (int i = t; i < NBUCK; i += 256) hist[i] = 0;
        __syncthreads();
        int base = blk * CHUNK;
        for (int e = base + t; e < base + CHUNK; e += 256)
            atomicAdd(&hist[dst[e] >> 7], 1);
        __syncthreads();
        for (int i = t; i < NBUCK; i += 256) {
            int c = hist[i];
            hist[i] = c ? atomicAdd(&bcount[i], c) : 0;   // reserve [base, base+c)
        }
        __syncthreads();
        for (int e = base + t; e < base + CHUNK; e += 256) {
            int d = dst[e];
            int bk = d >> 7;
            int pos = atomicAdd(&hist[bk], 1);
            part[bk * CAP + pos] = (unsigned)src[e] | ((unsigned)(d & 127) << 16);
        }
    }
}

// per-bucket: local deg + LDS scan -> nbeg/nend, then localized csr scatter (ushort)
__global__ __launch_bounds__(256)
void bucket_csr(const unsigned* __restrict__ part, const int* __restrict__ bcount,
                int* __restrict__ nbeg, int* __restrict__ nend,
                unsigned short* __restrict__ csr) {
    __shared__ int ldeg[128];
    __shared__ int lcur[128];
    __shared__ int w0s;
    int bk = blockIdx.x;
    int t = threadIdx.x;
    int cnt = bcount[bk];
    int base = bk * CAP;
    if (t < 128) ldeg[t] = 0;
    __syncthreads();
    for (int e = t; e < cnt; e += 256)
        atomicAdd(&ldeg[part[base + e] >> 16], 1);
    __syncthreads();
    int lane = t & 63, wid = t >> 6;
    int v = (t < 128) ? ldeg[t] : 0;
    int s = v;
#pragma unroll
    for (int off = 1; off < 64; off <<= 1) {
        int u = __shfl_up(s, off, 64);
        if (lane >= off) s += u;
    }
    if (t == 63) w0s = s;
    __syncthreads();
    if (t < 128) {
        int excl = s - v + ((wid == 1) ? w0s : 0);
        int node = bk * 128 + t;
        int b0 = base + excl;
        if (node < N_NODES) { nbeg[node] = b0; nend[node] = b0 + v; }
        lcur[t] = b0;
    }
    __syncthreads();
    for (int e = t; e < cnt; e += 256) {
        unsigned p = part[base + e];
        int pos = atomicAdd(&lcur[p >> 16], 1);
        csr[pos] = (unsigned short)(p & 0xFFFFu);
    }
}

// gather-mean from packed bf16 h; one wave per node, lane holds 2 elems (1 uint).
// Inner loop batched x8 for memory-level parallelism. ushort neighbor indices.
__global__ void aggregate_bf16(const int* __restrict__ nbeg, const int* __restrict__ nend,
                               const unsigned short* __restrict__ csr_src,
                               const unsigned* __restrict__ hb,
                               unsigned* __restrict__ aggb) {
    int wv   = (blockIdx.x * blockDim.x + threadIdx.x) >> 6;
    int lane = threadIdx.x & 63;
    if (wv >= N_NODES) return;
    int beg = nbeg[wv], end = nend[wv];
    float ax0 = 0.f, ay0 = 0.f, ax1 = 0.f, ay1 = 0.f;
    float ax2 = 0.f, ay2 = 0.f, ax3 = 0.f, ay3 = 0.f;
    for (int b = beg; b < end; b += 64) {
        int cnt = min(64, end - b);
        int idx = (b + lane < end) ? (int)csr_src[b + lane] : 0;
        int j = 0;
        for (; j + 8 <= cnt; j += 8) {
            int s0 = __shfl(idx, j,     64);
            int s1 = __shfl(idx, j + 1, 64);
            int s2 = __shfl(idx, j + 2, 64);
            int s3 = __shfl(idx, j + 3, 64);
            int s4 = __shfl(idx, j + 4, 64);
            int s5 = __shfl(idx, j + 5, 64);
            int s6 = __shfl(idx, j + 6, 64);
            int s7 = __shfl(idx, j + 7, 64);
            unsigned v0 = hb[s0 * 64 + lane];
            unsigned v1 = hb[s1 * 64 + lane];
            unsigned v2 = hb[s2 * 64 + lane];
            unsigned v3 = hb[s3 * 64 + lane];
            unsigned v4 = hb[s4 * 64 + lane];
            unsigned v5 = hb[s5 * 64 + lane];
            unsigned v6 = hb[s6 * 64 + lane];
            unsigned v7 = hb[s7 * 64 + lane];
            ax0 += bf_lo(v0); ay0 += bf_hi(v0);
            ax1 += bf_lo(v1); ay1 += bf_hi(v1);
            ax2 += bf_lo(v2); ay2 += bf_hi(v2);
            ax3 += bf_lo(v3); ay3 += bf_hi(v3);
            ax0 += bf_lo(v4); ay0 += bf_hi(v4);
            ax1 += bf_lo(v5); ay1 += bf_hi(v5);
            ax2 += bf_lo(v6); ay2 += bf_hi(v6);
            ax3 += bf_lo(v7); ay3 += bf_hi(v7);
        }
        for (; j + 2 <= cnt; j += 2) {
            int s0 = __shfl(idx, j,     64);
            int s1 = __shfl(idx, j + 1, 64);
            unsigned v0 = hb[s0 * 64 + lane];
            unsigned v1 = hb[s1 * 64 + lane];
            ax0 += bf_lo(v0); ay0 += bf_hi(v0);
            ax1 += bf_lo(v1); ay1 += bf_hi(v1);
        }
        if (j < cnt) {
            int s = __shfl(idx, j, 64);
            unsigned v = hb[s * 64 + lane];
            ax0 += bf_lo(v); ay0 += bf_hi(v);
        }
    }
    float rd = 1.0f / fmaxf((float)(end - beg), 1.0f);
    aggb[wv * 64 + lane] =
        pack_bf16x2(((ax0 + ax1) + (ax2 + ax3)) * rd,
                    ((ay0 + ay1) + (ay2 + ay3)) * rd);
}

// out = relu?( aggb@Wl + hb@Wr + b ); both A terms bf16-exact -> 2 MFMAs each (W hi/lo).
template <int RELU, int WRITE_F32, int WRITE_BF16>
__global__ __launch_bounds__(256)
void linear_mfma(const unsigned* __restrict__ aggb,
                 const unsigned* __restrict__ hbself,
                 const unsigned short* __restrict__ WfH,
                 const unsigned short* __restrict__ WfL,
                 const float* __restrict__ b,
                 float* __restrict__ out,
                 unsigned short* __restrict__ outb) {
    int tid  = threadIdx.x;
    int lane = tid & 63;
    int w    = tid >> 6;
    int row0 = blockIdx.x * 64 + (w & 1) * 32;
    int colhalf = w >> 1;
    int nt0 = colhalf * 2;
    int mc = min(row0 + (lane & 31), N_NODES - 1);
    int kh = lane >> 5;

    floatx16 acc0, acc1;
#pragma unroll
    for (int i = 0; i < 16; ++i) { acc0[i] = 0.f; acc1[i] = 0.f; }

    // A fragment for k-slice ks: bf16 elems ks*16+kh*8 .. +7 = uints ks*8+kh*4 .. +3
    const unsigned* arow = aggb   + (size_t)mc * 64 + kh * 4;
    const unsigned* hrow = hbself + (size_t)mc * 64 + kh * 4;

    // phase 0: agg term
#pragma unroll
    for (int ks = 0; ks < 8; ++ks) {
        short8 aa = *(const short8*)(arow + ks * 8);
        int cbase = (ks * 4 + nt0) * 64 + lane;
        short8 bh0 = *(const short8*)(WfH + (size_t)cbase * 8);
        short8 bl0 = *(const short8*)(WfL + (size_t)cbase * 8);
        short8 bh1 = *(const short8*)(WfH + (size_t)(cbase + 64) * 8);
        short8 bl1 = *(const short8*)(WfL + (size_t)(cbase + 64) * 8);
        acc0 = __builtin_amdgcn_mfma_f32_32x32x16_bf16(aa, bh0, acc0, 0, 0, 0);
        acc0 = __builtin_amdgcn_mfma_f32_32x32x16_bf16(aa, bl0, acc0, 0, 0, 0);
        acc1 = __builtin_amdgcn_mfma_f32_32x32x16_bf16(aa, bh1, acc1, 0, 0, 0);
        acc1 = __builtin_amdgcn_mfma_f32_32x32x16_bf16(aa, bl1, acc1, 0, 0, 0);
    }
    // phase 1: self term
#pragma unroll
    for (int ks = 0; ks < 8; ++ks) {
        short8 aa = *(const short8*)(hrow + ks * 8);
        int cbase = ((8 + ks) * 4 + nt0) * 64 + lane;
        short8 bh0 = *(const short8*)(WfH + (size_t)cbase * 8);
        short8 bl0 = *(const short8*)(WfL + (size_t)cbase * 8);
        short8 bh1 = *(const short8*)(WfH + (size_t)(cbase + 64) * 8);
        short8 bl1 = *(const short8*)(WfL + (size_t)(cbase + 64) * 8);
        acc0 = __builtin_amdgcn_mfma_f32_32x32x16_bf16(aa, bh0, acc0, 0, 0, 0);
        acc0 = __builtin_amdgcn_mfma_f32_32x32x16_bf16(aa, bl0, acc0, 0, 0, 0);
        acc1 = __builtin_amdgcn_mfma_f32_32x32x16_bf16(aa, bh1, acc1, 0, 0, 0);
        acc1 = __builtin_amdgcn_mfma_f32_32x32x16_bf16(aa, bl1, acc1, 0, 0, 0);
    }

    int col0 = colhalf * 64 + (lane & 31);
    float b0 = b[col0], b1 = b[col0 + 32];
#pragma unroll
    for (int reg = 0; reg < 16; ++reg) {
        int rloc = (reg & 3) + 8 * (reg >> 2) + 4 * kh;   // C/D row map (m74/m101)
        int rowg = row0 + rloc;
        if (rowg < N_NODES) {
            float v0 = acc0[reg] + b0;
            float v1 = acc1[reg] + b1;
            if (RELU) { v0 = fmaxf(v0, 0.f); v1 = fmaxf(v1, 0.f); }
            if (WRITE_F32) {
                out[(size_t)rowg * DIM + col0]      = v0;
                out[(size_t)rowg * DIM + col0 + 32] = v1;
            }
            if (WRITE_BF16) {
                outb[(size_t)rowg * DIM + col0]      = f32_to_bf16(v0);
                outb[(size_t)rowg * DIM + col0 + 32] = f32_to_bf16(v1);
            }
        }
    }
}

// logits from fp32 h2; 16 lanes/edge, 2xfloat4 per endpoint row (4 edges/wave, 8 loads in flight)
__global__ void edge_dot(const int* __restrict__ esrc, const int* __restrict__ edst,
                         const float* __restrict__ h2, float* __restrict__ out) {
    int t = blockIdx.x * blockDim.x + threadIdx.x;
    int e = t >> 4, c = t & 15;
    if (e >= N_LABEL) return;
    const float4* H = (const float4*)h2;
    int rs = esrc[e], rd = edst[e];
    float4 a0 = H[rs * 32 + 2 * c];
    float4 a1 = H[rs * 32 + 2 * c + 1];
    float4 b0 = H[rd * 32 + 2 * c];
    float4 b1 = H[rd * 32 + 2 * c + 1];
    float p = a0.x * b0.x + a0.y * b0.y + a0.z * b0.z + a0.w * b0.w
            + a1.x * b1.x + a1.y * b1.y + a1.z * b1.z + a1.w * b1.w;
#pragma unroll
    for (int off = 8; off; off >>= 1) p += __shfl_down(p, off, 16);
    if (c == 0) out[e] = p;
}

extern "C" void kernel_launch(void* const* d_in, const int* in_sizes, int n_in,
                              void* d_out, int out_size, void* d_ws, size_t ws_size,
                              hipStream_t stream) {
    const int*   n_id     = (const int*)d_in[0];
    const float* x_struct = (const float*)d_in[1];
    const int*   e_idx    = (const int*)d_in[2];   // [2, N_EDGES]
    const int*   eli      = (const int*)d_in[3];   // [2, N_LABEL]
    const float* emb      = (const float*)d_in[4];
    const float* W1l      = (const float*)d_in[5];
    const float* W1r      = (const float*)d_in[6];
    const float* b1       = (const float*)d_in[7];
    const float* W2l      = (const float*)d_in[8];
    const float* W2r      = (const float*)d_in[9];
    const float* b2       = (const float*)d_in[10];
    float* out = (float*)d_out;

    const int* src = e_idx;
    const int* dst = e_idx + N_EDGES;

    const size_t HN = (size_t)N_NODES * DIM;       // 6.4M elems
    float* h2     = (float*)d_ws;                  // fp32 (edge_dot accuracy)
    unsigned* aggb= (unsigned*)(h2 + HN);          // N_NODES*64 uints (bf16 agg)
    unsigned* hb0 = aggb + (size_t)N_NODES * 64;   // bf16 h0
    unsigned* hb1 = hb0 + (size_t)N_NODES * 64;    // bf16 h1
    int*   nbeg   = (int*)(hb1 + (size_t)N_NODES * 64);
    int*   nend   = nbeg + N_NODES;
    int*   bcount = nend + N_NODES;                // NBUCK
    unsigned* part= (unsigned*)(bcount + NBUCK);   // NBUCK*CAP packed (src | local<<16)
    unsigned short* csr = (unsigned short*)(part + NBUCK * CAP);  // NBUCK*CAP ushort
    uintptr_t wa  = ((uintptr_t)(csr + NBUCK * CAP) + 15) & ~(uintptr_t)15;
    unsigned short* WfH = (unsigned short*)wa;     // 2*32768
    unsigned short* WfL = WfH + 2 * 32768;

    hipMemsetAsync(bcount, 0, NBUCK * sizeof(int), stream);

    // fused: build hb0 + W swizzle + partition scatter (independent work, one dispatch)
    build_part<<<6532, 256, 0, stream>>>(n_id, emb, x_struct, hb0,
                                         W1l, W1r, W2l, W2r, WfH, WfL,
                                         src, dst, bcount, part);

    bucket_csr<<<NBUCK, 256, 0, stream>>>(part, bcount, nbeg, nend, csr);

    // layer 1: bf16 h1 only
    aggregate_bf16<<<(N_NODES * 64 + 255) / 256, 256, 0, stream>>>(nbeg, nend, csr, hb0, aggb);
    linear_mfma<1, 0, 1><<<(N_NODES + 63) / 64, 256, 0, stream>>>(
        aggb, hb0, WfH, WfL, b1, nullptr, (unsigned short*)hb1);

    // layer 2: fp32 h2 only (edge_dot reads fp32 for accuracy margin)
    aggregate_bf16<<<(N_NODES * 64 + 255) / 256, 256, 0, stream>>>(nbeg, nend, csr, hb1, aggb);
    linear_mfma<0, 1, 0><<<(N_NODES + 63) / 64, 256, 0, stream>>>(
        aggb, hb1, WfH + 32768, WfL + 32768, b2, h2, nullptr);

    edge_dot<<<(N_LABEL * 16 + 255) / 256, 256, 0, stream>>>(eli, eli + N_LABEL, h2, out);
}

// Round 14
// 241.082 us; speedup vs baseline: 1.0553x; 1.0553x over previous
//
#include <hip/hip_runtime.h>

#define N_NODES 50000
#define DIM     128
#define N_EDGES 800000
#define N_LABEL 200000

// bucket partition: bucket = dst >> 7 (128 nodes/bucket), fixed capacity slots
#define NBUCK 391            // ceil(50000/128)
#define CAP   4096           // slots per bucket (mean fill ~2046, 40-sigma margin)
#define NPBLK 250            // partition blocks
#define CHUNK 3200           // edges per partition block

typedef __attribute__((ext_vector_type(8)))  short short8;    // 8 bf16 (4 VGPRs)
typedef __attribute__((ext_vector_type(16))) float floatx16;  // 32x32 MFMA acc

// split fp32 into bf16 hi + bf16 lo (x ~= hi + lo, rel err ~2^-17), RNE both
__device__ inline void f32_to_bf16x2(float x, unsigned short& hi, unsigned short& lo) {
    unsigned u  = __float_as_uint(x);
    unsigned rh = (u + 0x7FFFu + ((u >> 16) & 1u)) >> 16;
    hi = (unsigned short)rh;
    float hif = __uint_as_float(rh << 16);
    float r = x - hif;
    unsigned ul = __float_as_uint(r);
    unsigned rl = (ul + 0x7FFFu + ((ul >> 16) & 1u)) >> 16;
    lo = (unsigned short)rl;
}

__device__ inline unsigned short f32_to_bf16(float x) {
    unsigned u = __float_as_uint(x);
    return (unsigned short)((u + 0x7FFFu + ((u >> 16) & 1u)) >> 16);
}

__device__ inline unsigned pack_bf16x2(float a, float b) {
    return (unsigned)f32_to_bf16(a) | ((unsigned)f32_to_bf16(b) << 16);
}

__device__ inline float bf_lo(unsigned u) { return __uint_as_float(u << 16); }
__device__ inline float bf_hi(unsigned u) { return __uint_as_float(u & 0xFFFF0000u); }

// fused: blocks [0,6250) build hb0 (bf16 only); [6250,6282) swizzle W; 6282 zeroes bcount
__global__ __launch_bounds__(256)
void build_h0_wf(const int* __restrict__ n_id,
                 const float* __restrict__ emb,
                 const float* __restrict__ xs,
                 unsigned* __restrict__ hb0,
                 const float* __restrict__ W1l, const float* __restrict__ W1r,
                 const float* __restrict__ W2l, const float* __restrict__ W2r,
                 unsigned short* __restrict__ WfH, unsigned short* __restrict__ WfL,
                 int* __restrict__ bcount) {
    if (blockIdx.x < 6250) {
        int t = blockIdx.x * 256 + threadIdx.x;     // < N_NODES*32 exactly
        int i = t >> 5, c = t & 31;
        float4 v;
        if (c < 16) {
            int nid = n_id[i];
            v = ((const float4*)emb)[nid * 16 + c];
        } else {
            v = ((const float4*)xs)[i * 16 + (c - 16)];
        }
        uint2 p;
        p.x = pack_bf16x2(v.x, v.y);
        p.y = pack_bf16x2(v.z, v.w);
        ((uint2*)hb0)[i * 32 + c] = p;
    } else if (blockIdx.x < 6282) {
        int t = (blockIdx.x - 6250) * 256 + threadIdx.x;   // 8192 chunks
        if (t >= 8192) return;
        int L  = t & 63;
        int nt = (t >> 6) & 3;
        int ks = (t >> 8) & 7;
        int p  = (t >> 11) & 1;
        int ly = t >> 12;
        const float* Ws[4] = {W1l, W1r, W2l, W2r};
        const float* W = Ws[ly * 2 + p];
        int n = nt * 32 + (L & 31);
        int kbase = ks * 16 + (L >> 5) * 8;
        short8 hv, lv;
#pragma unroll
        for (int j = 0; j < 8; ++j) {
            unsigned short hh, ll;
            f32_to_bf16x2(W[(kbase + j) * DIM + n], hh, ll);
            hv[j] = (short)hh;
            lv[j] = (short)ll;
        }
        *(short8*)(WfH + (size_t)t * 8) = hv;
        *(short8*)(WfL + (size_t)t * 8) = lv;
    } else {
        for (int i = threadIdx.x; i < NBUCK; i += 256) bcount[i] = 0;
    }
}

// fused hist + range-reserve + grouped scatter (no global scan).
// part record: src | (dst&127)<<16   (src < 2^16)
__global__ __launch_bounds__(256)
void part_scatter(const int* __restrict__ src, const int* __restrict__ dst,
                  int* __restrict__ bcount, unsigned* __restrict__ part) {
    __shared__ int hist[NBUCK];      // pass1: counts; pass2: write cursors
    int t = threadIdx.x;
    for (int i = t; i < NBUCK; i += 256) hist[i] = 0;
    __syncthreads();
    int base = blockIdx.x * CHUNK;
    for (int e = base + t; e < base + CHUNK; e += 256)
        atomicAdd(&hist[dst[e] >> 7], 1);
    __syncthreads();
    for (int i = t; i < NBUCK; i += 256) {
        int c = hist[i];
        hist[i] = c ? atomicAdd(&bcount[i], c) : 0;   // reserve [base, base+c)
    }
    __syncthreads();
    for (int e = base + t; e < base + CHUNK; e += 256) {
        int d = dst[e];
        int bk = d >> 7;
        int pos = atomicAdd(&hist[bk], 1);
        part[bk * CAP + pos] = (unsigned)src[e] | ((unsigned)(d & 127) << 16);
    }
}

// per-bucket: local deg + LDS scan -> nbeg/nend, then localized csr scatter (ushort)
__global__ __launch_bounds__(256)
void bucket_csr(const unsigned* __restrict__ part, const int* __restrict__ bcount,
                int* __restrict__ nbeg, int* __restrict__ nend,
                unsigned short* __restrict__ csr) {
    __shared__ int ldeg[128];
    __shared__ int lcur[128];
    __shared__ int w0s;
    int bk = blockIdx.x;
    int t = threadIdx.x;
    int cnt = bcount[bk];
    int base = bk * CAP;
    if (t < 128) ldeg[t] = 0;
    __syncthreads();
    for (int e = t; e < cnt; e += 256)
        atomicAdd(&ldeg[part[base + e] >> 16], 1);
    __syncthreads();
    int lane = t & 63, wid = t >> 6;
    int v = (t < 128) ? ldeg[t] : 0;
    int s = v;
#pragma unroll
    for (int off = 1; off < 64; off <<= 1) {
        int u = __shfl_up(s, off, 64);
        if (lane >= off) s += u;
    }
    if (t == 63) w0s = s;
    __syncthreads();
    if (t < 128) {
        int excl = s - v + ((wid == 1) ? w0s : 0);
        int node = bk * 128 + t;
        int b0 = base + excl;
        if (node < N_NODES) { nbeg[node] = b0; nend[node] = b0 + v; }
        lcur[t] = b0;
    }
    __syncthreads();
    for (int e = t; e < cnt; e += 256) {
        unsigned p = part[base + e];
        int pos = atomicAdd(&lcur[p >> 16], 1);
        csr[pos] = (unsigned short)(p & 0xFFFFu);
    }
}

// gather-mean from packed bf16 h; one wave per node, lane holds 2 elems (1 uint).
// Inner loop batched x8 for memory-level parallelism. ushort neighbor indices.
__global__ void aggregate_bf16(const int* __restrict__ nbeg, const int* __restrict__ nend,
                               const unsigned short* __restrict__ csr_src,
                               const unsigned* __restrict__ hb,
                               unsigned* __restrict__ aggb) {
    int wv   = (blockIdx.x * blockDim.x + threadIdx.x) >> 6;
    int lane = threadIdx.x & 63;
    if (wv >= N_NODES) return;
    int beg = nbeg[wv], end = nend[wv];
    float ax0 = 0.f, ay0 = 0.f, ax1 = 0.f, ay1 = 0.f;
    float ax2 = 0.f, ay2 = 0.f, ax3 = 0.f, ay3 = 0.f;
    for (int b = beg; b < end; b += 64) {
        int cnt = min(64, end - b);
        int idx = (b + lane < end) ? (int)csr_src[b + lane] : 0;
        int j = 0;
        for (; j + 8 <= cnt; j += 8) {
            int s0 = __shfl(idx, j,     64);
            int s1 = __shfl(idx, j + 1, 64);
            int s2 = __shfl(idx, j + 2, 64);
            int s3 = __shfl(idx, j + 3, 64);
            int s4 = __shfl(idx, j + 4, 64);
            int s5 = __shfl(idx, j + 5, 64);
            int s6 = __shfl(idx, j + 6, 64);
            int s7 = __shfl(idx, j + 7, 64);
            unsigned v0 = hb[s0 * 64 + lane];
            unsigned v1 = hb[s1 * 64 + lane];
            unsigned v2 = hb[s2 * 64 + lane];
            unsigned v3 = hb[s3 * 64 + lane];
            unsigned v4 = hb[s4 * 64 + lane];
            unsigned v5 = hb[s5 * 64 + lane];
            unsigned v6 = hb[s6 * 64 + lane];
            unsigned v7 = hb[s7 * 64 + lane];
            ax0 += bf_lo(v0); ay0 += bf_hi(v0);
            ax1 += bf_lo(v1); ay1 += bf_hi(v1);
            ax2 += bf_lo(v2); ay2 += bf_hi(v2);
            ax3 += bf_lo(v3); ay3 += bf_hi(v3);
            ax0 += bf_lo(v4); ay0 += bf_hi(v4);
            ax1 += bf_lo(v5); ay1 += bf_hi(v5);
            ax2 += bf_lo(v6); ay2 += bf_hi(v6);
            ax3 += bf_lo(v7); ay3 += bf_hi(v7);
        }
        for (; j + 2 <= cnt; j += 2) {
            int s0 = __shfl(idx, j,     64);
            int s1 = __shfl(idx, j + 1, 64);
            unsigned v0 = hb[s0 * 64 + lane];
            unsigned v1 = hb[s1 * 64 + lane];
            ax0 += bf_lo(v0); ay0 += bf_hi(v0);
            ax1 += bf_lo(v1); ay1 += bf_hi(v1);
        }
        if (j < cnt) {
            int s = __shfl(idx, j, 64);
            unsigned v = hb[s * 64 + lane];
            ax0 += bf_lo(v); ay0 += bf_hi(v);
        }
    }
    float rd = 1.0f / fmaxf((float)(end - beg), 1.0f);
    aggb[wv * 64 + lane] =
        pack_bf16x2(((ax0 + ax1) + (ax2 + ax3)) * rd,
                    ((ay0 + ay1) + (ay2 + ay3)) * rd);
}

// out = relu?( aggb@Wl + hb@Wr + b ); both A terms bf16-exact -> 2 MFMAs each (W hi/lo).
template <int RELU, int WRITE_F32, int WRITE_BF16>
__global__ __launch_bounds__(256)
void linear_mfma(const unsigned* __restrict__ aggb,
                 const unsigned* __restrict__ hbself,
                 const unsigned short* __restrict__ WfH,
                 const unsigned short* __restrict__ WfL,
                 const float* __restrict__ b,
                 float* __restrict__ out,
                 unsigned short* __restrict__ outb) {
    int tid  = threadIdx.x;
    int lane = tid & 63;
    int w    = tid >> 6;
    int row0 = blockIdx.x * 64 + (w & 1) * 32;
    int colhalf = w >> 1;
    int nt0 = colhalf * 2;
    int mc = min(row0 + (lane & 31), N_NODES - 1);
    int kh = lane >> 5;

    floatx16 acc0, acc1;
#pragma unroll
    for (int i = 0; i < 16; ++i) { acc0[i] = 0.f; acc1[i] = 0.f; }

    // A fragment for k-slice ks: bf16 elems ks*16+kh*8 .. +7 = uints ks*8+kh*4 .. +3
    const unsigned* arow = aggb   + (size_t)mc * 64 + kh * 4;
    const unsigned* hrow = hbself + (size_t)mc * 64 + kh * 4;

    // phase 0: agg term
#pragma unroll
    for (int ks = 0; ks < 8; ++ks) {
        short8 aa = *(const short8*)(arow + ks * 8);
        int cbase = (ks * 4 + nt0) * 64 + lane;
        short8 bh0 = *(const short8*)(WfH + (size_t)cbase * 8);
        short8 bl0 = *(const short8*)(WfL + (size_t)cbase * 8);
        short8 bh1 = *(const short8*)(WfH + (size_t)(cbase + 64) * 8);
        short8 bl1 = *(const short8*)(WfL + (size_t)(cbase + 64) * 8);
        acc0 = __builtin_amdgcn_mfma_f32_32x32x16_bf16(aa, bh0, acc0, 0, 0, 0);
        acc0 = __builtin_amdgcn_mfma_f32_32x32x16_bf16(aa, bl0, acc0, 0, 0, 0);
        acc1 = __builtin_amdgcn_mfma_f32_32x32x16_bf16(aa, bh1, acc1, 0, 0, 0);
        acc1 = __builtin_amdgcn_mfma_f32_32x32x16_bf16(aa, bl1, acc1, 0, 0, 0);
    }
    // phase 1: self term
#pragma unroll
    for (int ks = 0; ks < 8; ++ks) {
        short8 aa = *(const short8*)(hrow + ks * 8);
        int cbase = ((8 + ks) * 4 + nt0) * 64 + lane;
        short8 bh0 = *(const short8*)(WfH + (size_t)cbase * 8);
        short8 bl0 = *(const short8*)(WfL + (size_t)cbase * 8);
        short8 bh1 = *(const short8*)(WfH + (size_t)(cbase + 64) * 8);
        short8 bl1 = *(const short8*)(WfL + (size_t)(cbase + 64) * 8);
        acc0 = __builtin_amdgcn_mfma_f32_32x32x16_bf16(aa, bh0, acc0, 0, 0, 0);
        acc0 = __builtin_amdgcn_mfma_f32_32x32x16_bf16(aa, bl0, acc0, 0, 0, 0);
        acc1 = __builtin_amdgcn_mfma_f32_32x32x16_bf16(aa, bh1, acc1, 0, 0, 0);
        acc1 = __builtin_amdgcn_mfma_f32_32x32x16_bf16(aa, bl1, acc1, 0, 0, 0);
    }

    int col0 = colhalf * 64 + (lane & 31);
    float b0 = b[col0], b1 = b[col0 + 32];
#pragma unroll
    for (int reg = 0; reg < 16; ++reg) {
        int rloc = (reg & 3) + 8 * (reg >> 2) + 4 * kh;   // C/D row map (m74/m101)
        int rowg = row0 + rloc;
        if (rowg < N_NODES) {
            float v0 = acc0[reg] + b0;
            float v1 = acc1[reg] + b1;
            if (RELU) { v0 = fmaxf(v0, 0.f); v1 = fmaxf(v1, 0.f); }
            if (WRITE_F32) {
                out[(size_t)rowg * DIM + col0]      = v0;
                out[(size_t)rowg * DIM + col0 + 32] = v1;
            }
            if (WRITE_BF16) {
                outb[(size_t)rowg * DIM + col0]      = f32_to_bf16(v0);
                outb[(size_t)rowg * DIM + col0 + 32] = f32_to_bf16(v1);
            }
        }
    }
}

// logits from fp32 h2; 16 lanes/edge, 2xfloat4 per endpoint row (4 edges/wave, 8 loads in flight)
__global__ void edge_dot(const int* __restrict__ esrc, const int* __restrict__ edst,
                         const float* __restrict__ h2, float* __restrict__ out) {
    int t = blockIdx.x * blockDim.x + threadIdx.x;
    int e = t >> 4, c = t & 15;
    if (e >= N_LABEL) return;
    const float4* H = (const float4*)h2;
    int rs = esrc[e], rd = edst[e];
    float4 a0 = H[rs * 32 + 2 * c];
    float4 a1 = H[rs * 32 + 2 * c + 1];
    float4 b0 = H[rd * 32 + 2 * c];
    float4 b1 = H[rd * 32 + 2 * c + 1];
    float p = a0.x * b0.x + a0.y * b0.y + a0.z * b0.z + a0.w * b0.w
            + a1.x * b1.x + a1.y * b1.y + a1.z * b1.z + a1.w * b1.w;
#pragma unroll
    for (int off = 8; off; off >>= 1) p += __shfl_down(p, off, 16);
    if (c == 0) out[e] = p;
}

extern "C" void kernel_launch(void* const* d_in, const int* in_sizes, int n_in,
                              void* d_out, int out_size, void* d_ws, size_t ws_size,
                              hipStream_t stream) {
    const int*   n_id     = (const int*)d_in[0];
    const float* x_struct = (const float*)d_in[1];
    const int*   e_idx    = (const int*)d_in[2];   // [2, N_EDGES]
    const int*   eli      = (const int*)d_in[3];   // [2, N_LABEL]
    const float* emb      = (const float*)d_in[4];
    const float* W1l      = (const float*)d_in[5];
    const float* W1r      = (const float*)d_in[6];
    const float* b1       = (const float*)d_in[7];
    const float* W2l      = (const float*)d_in[8];
    const float* W2r      = (const float*)d_in[9];
    const float* b2       = (const float*)d_in[10];
    float* out = (float*)d_out;

    const int* src = e_idx;
    const int* dst = e_idx + N_EDGES;

    const size_t HN = (size_t)N_NODES * DIM;       // 6.4M elems
    float* h2     = (float*)d_ws;                  // fp32 (edge_dot accuracy)
    unsigned* aggb= (unsigned*)(h2 + HN);          // N_NODES*64 uints (bf16 agg)
    unsigned* hb0 = aggb + (size_t)N_NODES * 64;   // bf16 h0
    unsigned* hb1 = hb0 + (size_t)N_NODES * 64;    // bf16 h1
    int*   nbeg   = (int*)(hb1 + (size_t)N_NODES * 64);
    int*   nend   = nbeg + N_NODES;
    int*   bcount = nend + N_NODES;                // NBUCK
    unsigned* part= (unsigned*)(bcount + NBUCK);   // NBUCK*CAP packed (src | local<<16)
    unsigned short* csr = (unsigned short*)(part + NBUCK * CAP);  // NBUCK*CAP ushort
    uintptr_t wa  = ((uintptr_t)(csr + NBUCK * CAP) + 15) & ~(uintptr_t)15;
    unsigned short* WfH = (unsigned short*)wa;     // 2*32768
    unsigned short* WfL = WfH + 2 * 32768;

    // build hb0 + W swizzle + bcount zero (bcount ready before part_scatter launches)
    build_h0_wf<<<6283, 256, 0, stream>>>(n_id, emb, x_struct, hb0,
                                          W1l, W1r, W2l, W2r, WfH, WfL, bcount);

    // CSR build: separate dispatches so the 250 heavy blocks get the whole device
    part_scatter<<<NPBLK, 256, 0, stream>>>(src, dst, bcount, part);
    bucket_csr<<<NBUCK, 256, 0, stream>>>(part, bcount, nbeg, nend, csr);

    // layer 1: bf16 h1 only
    aggregate_bf16<<<(N_NODES * 64 + 255) / 256, 256, 0, stream>>>(nbeg, nend, csr, hb0, aggb);
    linear_mfma<1, 0, 1><<<(N_NODES + 63) / 64, 256, 0, stream>>>(
        aggb, hb0, WfH, WfL, b1, nullptr, (unsigned short*)hb1);

    // layer 2: fp32 h2 only (edge_dot reads fp32 for accuracy margin)
    aggregate_bf16<<<(N_NODES * 64 + 255) / 256, 256, 0, stream>>>(nbeg, nend, csr, hb1, aggb);
    linear_mfma<0, 1, 0><<<(N_NODES + 63) / 64, 256, 0, stream>>>(
        aggb, hb1, WfH + 32768, WfL + 32768, b2, h2, nullptr);

    edge_dot<<<(N_LABEL * 16 + 255) / 256, 256, 0, stream>>>(eli, eli + N_LABEL, h2, out);
}

// Round 15
// 239.373 us; speedup vs baseline: 1.0628x; 1.0071x over previous
//
#include <hip/hip_runtime.h>

#define N_NODES 50000
#define DIM     128
#define N_EDGES 800000
#define N_LABEL 200000

// bucket partition: bucket = dst >> 7 (128 nodes/bucket), fixed capacity slots
#define NBUCK 391            // ceil(50000/128)
#define CAP   4096           // slots per bucket (mean fill ~2046, 40-sigma margin)
#define NPBLK 250            // partition blocks
#define CHUNK 3200           // edges per partition block

typedef __attribute__((ext_vector_type(8)))  short short8;    // 8 bf16 (4 VGPRs)
typedef __attribute__((ext_vector_type(16))) float floatx16;  // 32x32 MFMA acc

// split fp32 into bf16 hi + bf16 lo (x ~= hi + lo, rel err ~2^-17), RNE both
__device__ inline void f32_to_bf16x2(float x, unsigned short& hi, unsigned short& lo) {
    unsigned u  = __float_as_uint(x);
    unsigned rh = (u + 0x7FFFu + ((u >> 16) & 1u)) >> 16;
    hi = (unsigned short)rh;
    float hif = __uint_as_float(rh << 16);
    float r = x - hif;
    unsigned ul = __float_as_uint(r);
    unsigned rl = (ul + 0x7FFFu + ((ul >> 16) & 1u)) >> 16;
    lo = (unsigned short)rl;
}

__device__ inline unsigned short f32_to_bf16(float x) {
    unsigned u = __float_as_uint(x);
    return (unsigned short)((u + 0x7FFFu + ((u >> 16) & 1u)) >> 16);
}

__device__ inline unsigned pack_bf16x2(float a, float b) {
    return (unsigned)f32_to_bf16(a) | ((unsigned)f32_to_bf16(b) << 16);
}

__device__ inline float bf_lo(unsigned u) { return __uint_as_float(u << 16); }
__device__ inline float bf_hi(unsigned u) { return __uint_as_float(u & 0xFFFF0000u); }

// fused: blocks [0,6250) build hb0 (bf16 only); [6250,6282) swizzle W; 6282 zeroes bcount
__global__ __launch_bounds__(256)
void build_h0_wf(const int* __restrict__ n_id,
                 const float* __restrict__ emb,
                 const float* __restrict__ xs,
                 unsigned* __restrict__ hb0,
                 const float* __restrict__ W1l, const float* __restrict__ W1r,
                 const float* __restrict__ W2l, const float* __restrict__ W2r,
                 unsigned short* __restrict__ WfH, unsigned short* __restrict__ WfL,
                 int* __restrict__ bcount) {
    if (blockIdx.x < 6250) {
        int t = blockIdx.x * 256 + threadIdx.x;     // < N_NODES*32 exactly
        int i = t >> 5, c = t & 31;
        float4 v;
        if (c < 16) {
            int nid = n_id[i];
            v = ((const float4*)emb)[nid * 16 + c];
        } else {
            v = ((const float4*)xs)[i * 16 + (c - 16)];
        }
        uint2 p;
        p.x = pack_bf16x2(v.x, v.y);
        p.y = pack_bf16x2(v.z, v.w);
        ((uint2*)hb0)[i * 32 + c] = p;
    } else if (blockIdx.x < 6282) {
        int t = (blockIdx.x - 6250) * 256 + threadIdx.x;   // 8192 chunks
        if (t >= 8192) return;
        int L  = t & 63;
        int nt = (t >> 6) & 3;
        int ks = (t >> 8) & 7;
        int p  = (t >> 11) & 1;
        int ly = t >> 12;
        const float* Ws[4] = {W1l, W1r, W2l, W2r};
        const float* W = Ws[ly * 2 + p];
        int n = nt * 32 + (L & 31);
        int kbase = ks * 16 + (L >> 5) * 8;
        short8 hv, lv;
#pragma unroll
        for (int j = 0; j < 8; ++j) {
            unsigned short hh, ll;
            f32_to_bf16x2(W[(kbase + j) * DIM + n], hh, ll);
            hv[j] = (short)hh;
            lv[j] = (short)ll;
        }
        *(short8*)(WfH + (size_t)t * 8) = hv;
        *(short8*)(WfL + (size_t)t * 8) = lv;
    } else {
        for (int i = threadIdx.x; i < NBUCK; i += 256) bcount[i] = 0;
    }
}

// fused hist + range-reserve + grouped scatter (no global scan).
// part record: src | (dst&127)<<16   (src < 2^16)
__global__ __launch_bounds__(256)
void part_scatter(const int* __restrict__ src, const int* __restrict__ dst,
                  int* __restrict__ bcount, unsigned* __restrict__ part) {
    __shared__ int hist[NBUCK];      // pass1: counts; pass2: write cursors
    int t = threadIdx.x;
    for (int i = t; i < NBUCK; i += 256) hist[i] = 0;
    __syncthreads();
    int base = blockIdx.x * CHUNK;
    for (int e = base + t; e < base + CHUNK; e += 256)
        atomicAdd(&hist[dst[e] >> 7], 1);
    __syncthreads();
    for (int i = t; i < NBUCK; i += 256) {
        int c = hist[i];
        hist[i] = c ? atomicAdd(&bcount[i], c) : 0;   // reserve [base, base+c)
    }
    __syncthreads();
    for (int e = base + t; e < base + CHUNK; e += 256) {
        int d = dst[e];
        int bk = d >> 7;
        int pos = atomicAdd(&hist[bk], 1);
        part[bk * CAP + pos] = (unsigned)src[e] | ((unsigned)(d & 127) << 16);
    }
}

// per-bucket: local deg + LDS scan -> nbeg/nend, then localized csr scatter (ushort)
__global__ __launch_bounds__(256)
void bucket_csr(const unsigned* __restrict__ part, const int* __restrict__ bcount,
                int* __restrict__ nbeg, int* __restrict__ nend,
                unsigned short* __restrict__ csr) {
    __shared__ int ldeg[128];
    __shared__ int lcur[128];
    __shared__ int w0s;
    int bk = blockIdx.x;
    int t = threadIdx.x;
    int cnt = bcount[bk];
    int base = bk * CAP;
    if (t < 128) ldeg[t] = 0;
    __syncthreads();
    for (int e = t; e < cnt; e += 256)
        atomicAdd(&ldeg[part[base + e] >> 16], 1);
    __syncthreads();
    int lane = t & 63, wid = t >> 6;
    int v = (t < 128) ? ldeg[t] : 0;
    int s = v;
#pragma unroll
    for (int off = 1; off < 64; off <<= 1) {
        int u = __shfl_up(s, off, 64);
        if (lane >= off) s += u;
    }
    if (t == 63) w0s = s;
    __syncthreads();
    if (t < 128) {
        int excl = s - v + ((wid == 1) ? w0s : 0);
        int node = bk * 128 + t;
        int b0 = base + excl;
        if (node < N_NODES) { nbeg[node] = b0; nend[node] = b0 + v; }
        lcur[t] = b0;
    }
    __syncthreads();
    for (int e = t; e < cnt; e += 256) {
        unsigned p = part[base + e];
        int pos = atomicAdd(&lcur[p >> 16], 1);
        csr[pos] = (unsigned short)(p & 0xFFFFu);
    }
}

// gather-mean from packed bf16 h: HALF-WAVE (32 lanes) per node, uint2 (8B) per lane.
// 2 nodes/wave -> 2 independent idx chains, 16 loads in flight per wave.
// Slot map slot=jj&3 preserved vs R14 -> bit-identical accumulation order.
__global__ void aggregate_bf16(const int* __restrict__ nbeg, const int* __restrict__ nend,
                               const unsigned short* __restrict__ csr_src,
                               const unsigned* __restrict__ hb,
                               unsigned* __restrict__ aggb) {
    int gtid = blockIdx.x * blockDim.x + threadIdx.x;
    int wv   = gtid >> 5;            // node id (one per half-wave)
    int lane = threadIdx.x & 63;
    int hbase = lane & 32;           // this half's lane base (0 or 32)
    int c = lane & 31;               // uint2 slot within the 256B row
    if (wv >= N_NODES) return;
    int beg = nbeg[wv], end = nend[wv];
    const uint2* H = (const uint2*)hb;
    float s00=0.f,s01=0.f,s02=0.f,s03=0.f;
    float s10=0.f,s11=0.f,s12=0.f,s13=0.f;
    float s20=0.f,s21=0.f,s22=0.f,s23=0.f;
    float s30=0.f,s31=0.f,s32=0.f,s33=0.f;
    for (int b = beg; b < end; b += 32) {
        int cnt = min(32, end - b);
        int idx = (b + c < end) ? (int)csr_src[b + c] : 0;
        int j = 0;
        for (; j + 8 <= cnt; j += 8) {
            int n0 = __shfl(idx, hbase + j,     64);
            int n1 = __shfl(idx, hbase + j + 1, 64);
            int n2 = __shfl(idx, hbase + j + 2, 64);
            int n3 = __shfl(idx, hbase + j + 3, 64);
            int n4 = __shfl(idx, hbase + j + 4, 64);
            int n5 = __shfl(idx, hbase + j + 5, 64);
            int n6 = __shfl(idx, hbase + j + 6, 64);
            int n7 = __shfl(idx, hbase + j + 7, 64);
            uint2 v0 = H[n0 * 32 + c];
            uint2 v1 = H[n1 * 32 + c];
            uint2 v2 = H[n2 * 32 + c];
            uint2 v3 = H[n3 * 32 + c];
            uint2 v4 = H[n4 * 32 + c];
            uint2 v5 = H[n5 * 32 + c];
            uint2 v6 = H[n6 * 32 + c];
            uint2 v7 = H[n7 * 32 + c];
            s00 += bf_lo(v0.x); s01 += bf_hi(v0.x); s02 += bf_lo(v0.y); s03 += bf_hi(v0.y);
            s10 += bf_lo(v1.x); s11 += bf_hi(v1.x); s12 += bf_lo(v1.y); s13 += bf_hi(v1.y);
            s20 += bf_lo(v2.x); s21 += bf_hi(v2.x); s22 += bf_lo(v2.y); s23 += bf_hi(v2.y);
            s30 += bf_lo(v3.x); s31 += bf_hi(v3.x); s32 += bf_lo(v3.y); s33 += bf_hi(v3.y);
            s00 += bf_lo(v4.x); s01 += bf_hi(v4.x); s02 += bf_lo(v4.y); s03 += bf_hi(v4.y);
            s10 += bf_lo(v5.x); s11 += bf_hi(v5.x); s12 += bf_lo(v5.y); s13 += bf_hi(v5.y);
            s20 += bf_lo(v6.x); s21 += bf_hi(v6.x); s22 += bf_lo(v6.y); s23 += bf_hi(v6.y);
            s30 += bf_lo(v7.x); s31 += bf_hi(v7.x); s32 += bf_lo(v7.y); s33 += bf_hi(v7.y);
        }
        for (; j + 2 <= cnt; j += 2) {
            int n0 = __shfl(idx, hbase + j,     64);
            int n1 = __shfl(idx, hbase + j + 1, 64);
            uint2 v0 = H[n0 * 32 + c];
            uint2 v1 = H[n1 * 32 + c];
            s00 += bf_lo(v0.x); s01 += bf_hi(v0.x); s02 += bf_lo(v0.y); s03 += bf_hi(v0.y);
            s10 += bf_lo(v1.x); s11 += bf_hi(v1.x); s12 += bf_lo(v1.y); s13 += bf_hi(v1.y);
        }
        if (j < cnt) {
            int n0 = __shfl(idx, hbase + j, 64);
            uint2 v0 = H[n0 * 32 + c];
            s00 += bf_lo(v0.x); s01 += bf_hi(v0.x); s02 += bf_lo(v0.y); s03 += bf_hi(v0.y);
        }
    }
    float rd = 1.0f / fmaxf((float)(end - beg), 1.0f);
    float f0 = ((s00 + s10) + (s20 + s30)) * rd;
    float f1 = ((s01 + s11) + (s21 + s31)) * rd;
    float f2 = ((s02 + s12) + (s22 + s32)) * rd;
    float f3 = ((s03 + s13) + (s23 + s33)) * rd;
    uint2 o;
    o.x = pack_bf16x2(f0, f1);
    o.y = pack_bf16x2(f2, f3);
    ((uint2*)aggb)[(size_t)wv * 32 + c] = o;
}

// out = relu?( aggb@Wl + hb@Wr + b ); both A terms bf16-exact -> 2 MFMAs each (W hi/lo).
template <int RELU, int WRITE_F32, int WRITE_BF16>
__global__ __launch_bounds__(256)
void linear_mfma(const unsigned* __restrict__ aggb,
                 const unsigned* __restrict__ hbself,
                 const unsigned short* __restrict__ WfH,
                 const unsigned short* __restrict__ WfL,
                 const float* __restrict__ b,
                 float* __restrict__ out,
                 unsigned short* __restrict__ outb) {
    int tid  = threadIdx.x;
    int lane = tid & 63;
    int w    = tid >> 6;
    int row0 = blockIdx.x * 64 + (w & 1) * 32;
    int colhalf = w >> 1;
    int nt0 = colhalf * 2;
    int mc = min(row0 + (lane & 31), N_NODES - 1);
    int kh = lane >> 5;

    floatx16 acc0, acc1;
#pragma unroll
    for (int i = 0; i < 16; ++i) { acc0[i] = 0.f; acc1[i] = 0.f; }

    // A fragment for k-slice ks: bf16 elems ks*16+kh*8 .. +7 = uints ks*8+kh*4 .. +3
    const unsigned* arow = aggb   + (size_t)mc * 64 + kh * 4;
    const unsigned* hrow = hbself + (size_t)mc * 64 + kh * 4;

    // phase 0: agg term
#pragma unroll
    for (int ks = 0; ks < 8; ++ks) {
        short8 aa = *(const short8*)(arow + ks * 8);
        int cbase = (ks * 4 + nt0) * 64 + lane;
        short8 bh0 = *(const short8*)(WfH + (size_t)cbase * 8);
        short8 bl0 = *(const short8*)(WfL + (size_t)cbase * 8);
        short8 bh1 = *(const short8*)(WfH + (size_t)(cbase + 64) * 8);
        short8 bl1 = *(const short8*)(WfL + (size_t)(cbase + 64) * 8);
        acc0 = __builtin_amdgcn_mfma_f32_32x32x16_bf16(aa, bh0, acc0, 0, 0, 0);
        acc0 = __builtin_amdgcn_mfma_f32_32x32x16_bf16(aa, bl0, acc0, 0, 0, 0);
        acc1 = __builtin_amdgcn_mfma_f32_32x32x16_bf16(aa, bh1, acc1, 0, 0, 0);
        acc1 = __builtin_amdgcn_mfma_f32_32x32x16_bf16(aa, bl1, acc1, 0, 0, 0);
    }
    // phase 1: self term
#pragma unroll
    for (int ks = 0; ks < 8; ++ks) {
        short8 aa = *(const short8*)(hrow + ks * 8);
        int cbase = ((8 + ks) * 4 + nt0) * 64 + lane;
        short8 bh0 = *(const short8*)(WfH + (size_t)cbase * 8);
        short8 bl0 = *(const short8*)(WfL + (size_t)cbase * 8);
        short8 bh1 = *(const short8*)(WfH + (size_t)(cbase + 64) * 8);
        short8 bl1 = *(const short8*)(WfL + (size_t)(cbase + 64) * 8);
        acc0 = __builtin_amdgcn_mfma_f32_32x32x16_bf16(aa, bh0, acc0, 0, 0, 0);
        acc0 = __builtin_amdgcn_mfma_f32_32x32x16_bf16(aa, bl0, acc0, 0, 0, 0);
        acc1 = __builtin_amdgcn_mfma_f32_32x32x16_bf16(aa, bh1, acc1, 0, 0, 0);
        acc1 = __builtin_amdgcn_mfma_f32_32x32x16_bf16(aa, bl1, acc1, 0, 0, 0);
    }

    int col0 = colhalf * 64 + (lane & 31);
    float b0 = b[col0], b1 = b[col0 + 32];
#pragma unroll
    for (int reg = 0; reg < 16; ++reg) {
        int rloc = (reg & 3) + 8 * (reg >> 2) + 4 * kh;   // C/D row map (m74/m101)
        int rowg = row0 + rloc;
        if (rowg < N_NODES) {
            float v0 = acc0[reg] + b0;
            float v1 = acc1[reg] + b1;
            if (RELU) { v0 = fmaxf(v0, 0.f); v1 = fmaxf(v1, 0.f); }
            if (WRITE_F32) {
                out[(size_t)rowg * DIM + col0]      = v0;
                out[(size_t)rowg * DIM + col0 + 32] = v1;
            }
            if (WRITE_BF16) {
                outb[(size_t)rowg * DIM + col0]      = f32_to_bf16(v0);
                outb[(size_t)rowg * DIM + col0 + 32] = f32_to_bf16(v1);
            }
        }
    }
}

// logits from fp32 h2; 16 lanes/edge, 2xfloat4 per endpoint row (4 edges/wave, 8 loads in flight)
__global__ void edge_dot(const int* __restrict__ esrc, const int* __restrict__ edst,
                         const float* __restrict__ h2, float* __restrict__ out) {
    int t = blockIdx.x * blockDim.x + threadIdx.x;
    int e = t >> 4, c = t & 15;
    if (e >= N_LABEL) return;
    const float4* H = (const float4*)h2;
    int rs = esrc[e], rd = edst[e];
    float4 a0 = H[rs * 32 + 2 * c];
    float4 a1 = H[rs * 32 + 2 * c + 1];
    float4 b0 = H[rd * 32 + 2 * c];
    float4 b1 = H[rd * 32 + 2 * c + 1];
    float p = a0.x * b0.x + a0.y * b0.y + a0.z * b0.z + a0.w * b0.w
            + a1.x * b1.x + a1.y * b1.y + a1.z * b1.z + a1.w * b1.w;
#pragma unroll
    for (int off = 8; off; off >>= 1) p += __shfl_down(p, off, 16);
    if (c == 0) out[e] = p;
}

extern "C" void kernel_launch(void* const* d_in, const int* in_sizes, int n_in,
                              void* d_out, int out_size, void* d_ws, size_t ws_size,
                              hipStream_t stream) {
    const int*   n_id     = (const int*)d_in[0];
    const float* x_struct = (const float*)d_in[1];
    const int*   e_idx    = (const int*)d_in[2];   // [2, N_EDGES]
    const int*   eli      = (const int*)d_in[3];   // [2, N_LABEL]
    const float* emb      = (const float*)d_in[4];
    const float* W1l      = (const float*)d_in[5];
    const float* W1r      = (const float*)d_in[6];
    const float* b1       = (const float*)d_in[7];
    const float* W2l      = (const float*)d_in[8];
    const float* W2r      = (const float*)d_in[9];
    const float* b2       = (const float*)d_in[10];
    float* out = (float*)d_out;

    const int* src = e_idx;
    const int* dst = e_idx + N_EDGES;

    const size_t HN = (size_t)N_NODES * DIM;       // 6.4M elems
    float* h2     = (float*)d_ws;                  // fp32 (edge_dot accuracy)
    unsigned* aggb= (unsigned*)(h2 + HN);          // N_NODES*64 uints (bf16 agg)
    unsigned* hb0 = aggb + (size_t)N_NODES * 64;   // bf16 h0
    unsigned* hb1 = hb0 + (size_t)N_NODES * 64;    // bf16 h1
    int*   nbeg   = (int*)(hb1 + (size_t)N_NODES * 64);
    int*   nend   = nbeg + N_NODES;
    int*   bcount = nend + N_NODES;                // NBUCK
    unsigned* part= (unsigned*)(bcount + NBUCK);   // NBUCK*CAP packed (src | local<<16)
    unsigned short* csr = (unsigned short*)(part + NBUCK * CAP);  // NBUCK*CAP ushort
    uintptr_t wa  = ((uintptr_t)(csr + NBUCK * CAP) + 15) & ~(uintptr_t)15;
    unsigned short* WfH = (unsigned short*)wa;     // 2*32768
    unsigned short* WfL = WfH + 2 * 32768;

    // build hb0 + W swizzle + bcount zero (bcount ready before part_scatter launches)
    build_h0_wf<<<6283, 256, 0, stream>>>(n_id, emb, x_struct, hb0,
                                          W1l, W1r, W2l, W2r, WfH, WfL, bcount);

    // CSR build: separate dispatches so the 250 heavy blocks get the whole device
    part_scatter<<<NPBLK, 256, 0, stream>>>(src, dst, bcount, part);
    bucket_csr<<<NBUCK, 256, 0, stream>>>(part, bcount, nbeg, nend, csr);

    // layer 1: bf16 h1 only  (half-wave/node aggregate: N_NODES*32 threads)
    aggregate_bf16<<<(N_NODES * 32 + 255) / 256, 256, 0, stream>>>(nbeg, nend, csr, hb0, aggb);
    linear_mfma<1, 0, 1><<<(N_NODES + 63) / 64, 256, 0, stream>>>(
        aggb, hb0, WfH, WfL, b1, nullptr, (unsigned short*)hb1);

    // layer 2: fp32 h2 only (edge_dot reads fp32 for accuracy margin)
    aggregate_bf16<<<(N_NODES * 32 + 255) / 256, 256, 0, stream>>>(nbeg, nend, csr, hb1, aggb);
    linear_mfma<0, 1, 0><<<(N_NODES + 63) / 64, 256, 0, stream>>>(
        aggb, hb1, WfH + 32768, WfL + 32768, b2, h2, nullptr);

    edge_dot<<<(N_LABEL * 16 + 255) / 256, 256, 0, stream>>>(eli, eli + N_LABEL, h2, out);
}